// Round 19
// baseline (381.390 us; speedup 1.0000x reference)
//
#include <hip/hip_runtime.h>

typedef __bf16 bf16x8 __attribute__((ext_vector_type(8)));
typedef float f32x4 __attribute__((ext_vector_type(4)));
typedef float f32x16 __attribute__((ext_vector_type(16)));

static __device__ __forceinline__ ushort f2b(float f) {
    uint32_t x = __float_as_uint(f);
    x += 0x7fffu + ((x >> 16) & 1u);   // RNE (finite values)
    return (ushort)(x >> 16);
}
static __device__ __forceinline__ float b2f(ushort u) {
    return __uint_as_float(((uint32_t)u) << 16);
}

typedef const __attribute__((address_space(1))) uint32_t gu32;
typedef __attribute__((address_space(3))) uint32_t lu32;
static __device__ __forceinline__ void gl_lds16(const void* g, void* l) {
    // async global->LDS: per-lane global src, wave-uniform LDS base + lane*16
    __builtin_amdgcn_global_load_lds((gu32*)g, (lu32*)l, 16, 0, 0);
}

// ---------------------------------------------------------------------------
// 1) adaptive_avg_pool2d(x, 3): one block per (b,c) plane. 96x96 -> 3x3.
__global__ __launch_bounds__(256) void pool_k(const float* __restrict__ x,
                                              float* __restrict__ pooled) {
    const int bc  = blockIdx.x;
    const int tid = threadIdx.x;
    const int lane = tid & 63, wv = tid >> 6;
    const float4* p4 = (const float4*)(x + (size_t)bc * 9216);
    __shared__ float red[4][9];
#pragma unroll
    for (int bi = 0; bi < 3; ++bi) {
#pragma unroll
        for (int bj = 0; bj < 3; ++bj) {
            int row = bi * 32 + (tid >> 3);
            int c4  = bj * 8 + (tid & 7);
            float4 f = p4[row * 24 + c4];
            float s = f.x + f.y + f.z + f.w;
#pragma unroll
            for (int off = 32; off; off >>= 1) s += __shfl_down(s, off);
            if (lane == 0) red[wv][bi * 3 + bj] = s;
        }
    }
    __syncthreads();
    if (tid < 9) {
        float s = red[0][tid] + red[1][tid] + red[2][tid] + red[3][tid];
        pooled[(size_t)bc * 9 + tid] = s * (1.0f / 1024.0f);
    }
}

// ---------------------------------------------------------------------------
// 2) gen = einsum('bcij,oc->boij', pooled, w_gen) + b_gen
__global__ __launch_bounds__(256) void gen_k(const float* __restrict__ pooled,
                                             const float* __restrict__ wgen,
                                             const float* __restrict__ bgen,
                                             float* __restrict__ gen) {
    __shared__ float pl[256];
    const int b = blockIdx.x / 9, ij = blockIdx.x % 9;
    const int o = threadIdx.x;
    pl[o] = pooled[((size_t)b * 256 + o) * 9 + ij];
    __syncthreads();
    float a = bgen[o];
    const float4* wg4 = (const float4*)(wgen + (size_t)o * 256);
    const float4* pl4 = (const float4*)pl;
#pragma unroll 4
    for (int q = 0; q < 64; ++q) {
        float4 w = wg4[q], p = pl4[q];
        a += w.x * p.x + w.y * p.y + w.z * p.z + w.w * p.w;
    }
    gen[((size_t)b * 256 + o) * 9 + ij] = a;
}

// ---------------------------------------------------------------------------
// 3) weight repack for 32x32x16 MFMA. wtr granule g (16B = 8 ushorts):
//    g = step*1024 + grp*64 + l, step = ch*9+tap, grp = t32*2+ks (16 groups),
//    l = lane. Content j: bf16(w_c1[o = t32*32 + (l&31)]
//                               [c = ch*32 + ks*16 + (l>>5)*8 + j][tap]).
//    A and B share the k-map (lane>>5)*8+j -> permutation-consistent.
__global__ __launch_bounds__(256) void wtr_k(const float* __restrict__ wc1,
                                             ushort* __restrict__ wtr) {
    int g = blockIdx.x * 256 + threadIdx.x;   // < 73728 granules
    int step = g >> 10;                       // 0..71
    int rem  = g & 1023;
    int grp  = rem >> 6;                      // 0..15
    int l    = rem & 63;
    int t32 = grp >> 1, ks = grp & 1;
    int ch = step / 9, tap = step - ch * 9;
    int o  = t32 * 32 + (l & 31);
    int cb = ch * 32 + ks * 16 + (l >> 5) * 8;
    ushort tmp[8];
#pragma unroll
    for (int j = 0; j < 8; ++j)
        tmp[j] = f2b(wc1[(size_t)o * 2304 + (size_t)(cb + j) * 9 + tap]);
    *(uint4*)(wtr + (size_t)g * 8) = *(const uint4*)tmp;
}

// ---------------------------------------------------------------------------
// 3b) xt_k: convoluted f32 [b][c][h][w] -> xt bf16 [b][h][px][c] (transposed),
//     via LDS. xt lives in d_out-as-scratch (dw_k overwrites d_out last).
//     Also zeroes the 8 KB "zeros" staging region (block 0).
__global__ __launch_bounds__(512) void xt_k(const float* __restrict__ xin,
                                            ushort* __restrict__ xt,
                                            ushort* __restrict__ zeros) {
    __shared__ ushort T[96][258];             // 49536 B, padded rows
    const int bh = blockIdx.x;                // b*96 + h
    const int b = bh / 96, h = bh % 96;
    const int tid = threadIdx.x;
    const float* src = xin + (size_t)b * 2359296 + (size_t)h * 96;
#pragma unroll
    for (int it = 0; it < 12; ++it) {
        int id = tid + it * 512;              // < 6144
        int c = id / 24, q = id - c * 24;     // q < 24
        float4 v = *(const float4*)(src + (size_t)c * 9216 + q * 4);
        int px = q * 4;
        T[px + 0][c] = f2b(v.x); T[px + 1][c] = f2b(v.y);
        T[px + 2][c] = f2b(v.z); T[px + 3][c] = f2b(v.w);
    }
    __syncthreads();
    ushort* dst = xt + (size_t)bh * 24576;
#pragma unroll
    for (int it = 0; it < 12; ++it) {
        int id = tid + it * 512;              // < 6144
        int px = id >> 6, cq = id & 63;
        ushort4 u;
        u.x = T[px][cq * 4 + 0]; u.y = T[px][cq * 4 + 1];
        u.z = T[px][cq * 4 + 2]; u.w = T[px][cq * 4 + 3];
        *(ushort4*)(dst + px * 256 + cq * 4) = u;
    }
    if (bh == 0) {                            // 8 KB zero region (512 x 16 B)
        uint4 zz; zz.x = zz.y = zz.z = zz.w = 0u;
        *(uint4*)(zeros + (size_t)tid * 8) = zz;
    }
}

// ---------------------------------------------------------------------------
// 4) conv3x3 (C=256->256), implicit GEMM, MFMA 32x32x16 bf16.
//    Block = (b, 1 row), 256 thr = 4 waves, wave = 64ch x 96px:
//    2 m x 3 n x f32x16 acc (96 AGPR). K-half-major B layout
//    Bl[row][ks][px 98][16c] -> conflict-free b128 reads (R18, verified).
//    REGISTER DIET for 3 streams/SIMD (512/3 = 170 regs; 96 AGPR -> VGPR
//    <= 74): A-ring depth 2 (32x32 step >= 384 cy MFMA issue >> 200 cy L2
//    latency), B-frags loaded per-ks (bfr[3] not [3][2]).
//    launch_bounds(256,3) -> 3 independent blocks/CU.
//    Epilogue: y[b][h][o][px] + BN partials (32-lane shfl + LDS gather).
__global__ __launch_bounds__(256, 3) void conv_k(const ushort* __restrict__ xt,
                                                 const ushort* __restrict__ wtr,
                                                 const float* __restrict__ bc1,
                                                 const ushort* __restrict__ zeros,
                                                 ushort* __restrict__ yb,
                                                 float* __restrict__ part) {
    __shared__ ushort Bl[2][9408];   // [buf][3 row][2 ks][98 px][16 c]

    const int blk0 = blockIdx.x;
    const int blk = (blk0 & 7) * 192 + (blk0 >> 3);  // XCD swizzle (1536=8*192)
    const int b = blk / 96, h = blk % 96;
    const int tid = threadIdx.x;
    const int lane = tid & 63, wv = tid >> 6;
    const int l31 = lane & 31, lh = lane >> 5;

    // zero pad px columns (idx 0,97): 2 bufs x 3 rows x 2 ks x 2 cols x 16 c
    {
        int z = tid;                           // 256 threads; need 384 writes
#pragma unroll
        for (int z0 = 0; z0 < 2; ++z0, z += 256) {
            if (z < 384) {
                int bsel = z >= 192, rem = z - bsel * 192;
                int row = rem >> 6, r6 = rem & 63;
                int ks = (r6 >> 5) & 1, pxp = ((r6 >> 4) & 1) ? 97 : 0,
                    c = r6 & 15;
                Bl[bsel][((row * 2 + ks) * 98 + pxp) * 16 + c] = 0;
            }
        }
    }

    // stage one chunk: 18 segs = 3 rows x 2 ks x 3 px-groups(32). Wave wv
    // does segs {wv, wv+4, ...}. Seg = 1KB lane-linear: px=lane>>1 within
    // group, c-half=lane&1 (8 ushorts).
    auto stage = [&](int chunk, int buf) {
#pragma unroll
        for (int j = 0; j < 5; ++j) {
            const int s = wv + j * 4;
            if (s < 18) {
                const int row = s / 6, r6 = s - (s / 6) * 6;
                const int ks = r6 / 3, pg = r6 - ks * 3;
                const int r = h + row - 1;
                const ushort* src = ((unsigned)r < 96u)
                    ? (xt + ((size_t)(b * 96 + r) * 96 + pg * 32
                             + (lane >> 1)) * 256
                          + chunk * 32 + ks * 16 + (lane & 1) * 8)
                    : (zeros + lane * 8);
                gl_lds16(src,
                         &Bl[buf][((row * 2 + ks) * 98 + 1 + pg * 32) * 16]);
            }
        }
    };

    // ---- A fragments: frag (mi,ks) = granule step*1024 + (wv*4+mi*2+ks)*64
    //      + lane. Per step: 4 frags = 4 KB/wave.
    const uint4* Abase = (const uint4*)wtr + wv * 256 + lane;

    f32x16 acc[2][3] = {};
    uint4 abuf[2][4];        // depth-2 ping-pong: slot = t & 1; frag = mi*2+ks

    // ---- prologue: stage chunk 0 -> buf0; A(step 0) -> slot 0
    stage(0, 0);
#pragma unroll
    for (int f = 0; f < 4; ++f) abuf[0][f] = Abase[f * 64];
    __syncthreads();   // drains DMA

    for (int k = 0; k < 4; ++k) {              // chunks 2k (buf0), 2k+1 (buf1)
#pragma unroll
        for (int t = 0; t < 18; ++t) {         // stp = k*18 + t; idx static
            const int cur = t & 1;
            if (t == 0) stage(2 * k + 1, 1);
            else if (t == 9 && k < 3) stage(2 * k + 2, 0);
            if (t < 17 || k < 3) {             // A prefetch stp+1 -> slot cur^1
                const uint4* Ap = Abase + (size_t)(k * 18 + t + 1) * 1024;
#pragma unroll
                for (int f = 0; f < 4; ++f)
                    abuf[cur ^ 1][f] = Ap[f * 64];
            }
            const int tap = (t < 9) ? t : t - 9;
            const int dy = tap / 3, dx = tap % 3;
            const ushort* Bb = &Bl[t >= 9][0];
#pragma unroll
            for (int ks = 0; ks < 2; ++ks) {
                bf16x8 bfr[3];
#pragma unroll
                for (int ni = 0; ni < 3; ++ni)
                    bfr[ni] = *(const bf16x8*)(Bb +
                        ((dy * 2 + ks) * 98 + ni * 32 + l31 + dx) * 16 + lh * 8);
#pragma unroll
                for (int mi = 0; mi < 2; ++mi) {
                    const bf16x8 af = *(const bf16x8*)&abuf[cur][mi * 2 + ks];
#pragma unroll
                    for (int ni = 0; ni < 3; ++ni)
                        acc[mi][ni] = __builtin_amdgcn_mfma_f32_32x32x16_bf16(
                            af, bfr[ni], acc[mi][ni], 0, 0, 0);
                }
            }
            if (t == 8) __syncthreads();               // buf1 ready, buf0 free
            else if (t == 17 && k < 3) __syncthreads();// buf0 ready, buf1 free
        }
    }

    // ---- epilogue: +bias, y store ([b][h][o][px]) + BN partials.
    //      D (verified): col = lane&31 (px), row = (r&3)+8*(r>>2)+4*(lane>>5)
    const size_t ybase = (size_t)blk * 24576;
    float* red = (float*)&Bl[0][0];           // 256 o x {s, s2}
    __syncthreads();                          // all MFMA reads of Bl done
#pragma unroll
    for (int mi = 0; mi < 2; ++mi) {
        const int ob = wv * 64 + mi * 32;
        float s[16], s2[16];
#pragma unroll
        for (int r = 0; r < 16; ++r) {
            const int o = ob + (r & 3) + 8 * (r >> 2) + 4 * lh;
            const float bias = bc1[o];
            float sv = 0.f, sv2 = 0.f;
#pragma unroll
            for (int ni = 0; ni < 3; ++ni) {
                float v = acc[mi][ni][r] + bias;
                yb[ybase + o * 96 + ni * 32 + l31] = f2b(v);
                sv += v; sv2 += v * v;
            }
            s[r] = sv; s2[r] = sv2;
        }
#pragma unroll
        for (int off = 1; off < 32; off <<= 1) {
#pragma unroll
            for (int r = 0; r < 16; ++r) {
                s[r]  += __shfl_xor(s[r], off);
                s2[r] += __shfl_xor(s2[r], off);
            }
        }
        if (l31 == 0) {
#pragma unroll
            for (int r = 0; r < 16; ++r) {
                const int ol = ob + (r & 3) + 8 * (r >> 2) + 4 * lh;
                red[ol * 2]     = s[r];
                red[ol * 2 + 1] = s2[r];
            }
        }
    }
    __syncthreads();
    {
        const int o = tid;                    // 256 threads = 256 channels
        part[(size_t)o * 1536 + blk]          = red[o * 2];
        part[393216 + (size_t)o * 1536 + blk] = red[o * 2 + 1];
    }
}

// ---------------------------------------------------------------------------
// 5) BN reduce + finalize: block = channel o; sum 1536 partials (coalesced)
__global__ __launch_bounds__(256) void bnred_k(const float* __restrict__ part,
                                               const float* __restrict__ gamma,
                                               const float* __restrict__ beta,
                                               float* __restrict__ bnp) {
    const int o = blockIdx.x, t = threadIdx.x;
    const float* p0 = part + (size_t)o * 1536;
    const float* p1 = p0 + 393216;
    float s = 0.f, s2 = 0.f;
#pragma unroll
    for (int k = 0; k < 6; ++k) { s += p0[t + k * 256]; s2 += p1[t + k * 256]; }
    const int lane = t & 63, wv = t >> 6;
#pragma unroll
    for (int off = 32; off; off >>= 1) {
        s  += __shfl_down(s, off);
        s2 += __shfl_down(s2, off);
    }
    __shared__ float r1[4], r2[4];
    if (lane == 0) { r1[wv] = s; r2[wv] = s2; }
    __syncthreads();
    if (t == 0) {
        float S  = r1[0] + r1[1] + r1[2] + r1[3];
        float S2 = r2[0] + r2[1] + r2[2] + r2[3];
        const float invN = 1.0f / 147456.0f;
        float mu  = S * invN;
        float var = S2 * invN - mu * mu;
        float sc  = gamma[o] * rsqrtf(var + 1e-5f);
        bnp[o]       = sc;
        bnp[256 + o] = beta[o] - mu * sc;
    }
}

// ---------------------------------------------------------------------------
// 6) depthwise 3x3, vectorized: padded LDS [98][104] f32 (zero halo, no
//    branches), each thread computes 4 outputs/iter from 9 ds_read_b128 +
//    36 FMA; float4 stores. yb layout [b][h][o][px] (row stride 24576).
__global__ __launch_bounds__(256) void dw_k(const ushort* __restrict__ yb,
                                            const float* __restrict__ gen,
                                            const float* __restrict__ bnp,
                                            float* __restrict__ out) {
    __shared__ float pl[98][104];                 // 40768 B
    const int bc = blockIdx.x, tid = threadIdx.x;
    const int b = bc >> 8, c = bc & 255;
    const float sc = bnp[c], sh = bnp[256 + c];

    // zero halo: rows 0 & 97 (104 each) + cols {0..3,100..103} rows 1..96
#pragma unroll
    for (int z0 = 0; z0 < 4; ++z0) {
        int z = tid + z0 * 256;
        if (z < 104) pl[0][z] = 0.f;
        else if (z < 208) pl[97][z - 104] = 0.f;
        else if (z < 976) {
            int w = z - 208;                      // < 768
            int r = (w >> 3) + 1, j = w & 7;
            pl[r][(j < 4) ? j : 96 + j] = 0.f;
        }
    }

    // stage plane with BN+ReLU: 2304 ushort4 items, 9 per thread
    const ushort4* yb4 = (const ushort4*)yb;
    const size_t pbase = (size_t)b * 589824 + c * 24;   // ushort4 units
#pragma unroll
    for (int it = 0; it < 9; ++it) {
        int e4 = tid + it * 256;                  // < 2304
        int row = e4 / 24, q = e4 - row * 24;
        ushort4 u = yb4[pbase + (size_t)row * 6144 + q];
        float4 f;
        f.x = fmaxf(b2f(u.x) * sc + sh, 0.f);
        f.y = fmaxf(b2f(u.y) * sc + sh, 0.f);
        f.z = fmaxf(b2f(u.z) * sc + sh, 0.f);
        f.w = fmaxf(b2f(u.w) * sc + sh, 0.f);
        *(float4*)&pl[row + 1][q * 4 + 4] = f;
    }
    float g[9];
    const float* gp = gen + (size_t)bc * 9;
#pragma unroll
    for (int k = 0; k < 9; ++k) g[k] = gp[k];
    __syncthreads();

    float4* op4 = (float4*)(out + (size_t)bc * 9216);
#pragma unroll
    for (int it = 0; it < 9; ++it) {
        int e4 = tid + it * 256;                  // < 2304
        int row = e4 / 24, q = e4 - row * 24;     // out row, col group 4q..4q+3
        float4 o4 = {0.f, 0.f, 0.f, 0.f};
#pragma unroll
        for (int dy = 0; dy < 3; ++dy) {
            const float4* pr = (const float4*)&pl[row + dy][0];
            float4 x0 = pr[q];                    // need .w  (col 4q-1)
            float4 x1 = pr[q + 1];                // cols 4q..4q+3
            float4 x2 = pr[q + 2];                // need .x  (col 4q+4)
            const float w0 = g[dy * 3 + 0], w1 = g[dy * 3 + 1],
                        w2 = g[dy * 3 + 2];
            o4.x += w0 * x0.w + w1 * x1.x + w2 * x1.y;
            o4.y += w0 * x1.x + w1 * x1.y + w2 * x1.z;
            o4.z += w0 * x1.y + w1 * x1.z + w2 * x1.w;
            o4.w += w0 * x1.z + w1 * x1.w + w2 * x2.x;
        }
        op4[e4] = o4;
    }
}

// ---------------------------------------------------------------------------
extern "C" void kernel_launch(void* const* d_in, const int* in_sizes, int n_in,
                              void* d_out, int out_size, void* d_ws, size_t ws_size,
                              hipStream_t stream) {
    const float* x       = (const float*)d_in[0];
    const float* conv_in = (const float*)d_in[1];
    const float* w_gen   = (const float*)d_in[2];
    const float* b_gen   = (const float*)d_in[3];
    const float* w_c1    = (const float*)d_in[4];
    const float* b_c1    = (const float*)d_in[5];
    const float* gamma   = (const float*)d_in[6];
    const float* beta    = (const float*)d_in[7];
    float* out = (float*)d_out;

    char* ws = (char*)d_ws;
    float*  pooled = (float*)(ws + 0);          // 147456 B
    float*  gen    = (float*)(ws + 147456);     // 147456 B
    ushort* wtr    = (ushort*)(ws + 294912);    // 1179648 B
    float*  part   = (float*)(ws + 1474560);    // 3145728 B
    float*  bnp    = (float*)(ws + 4620288);    // 2048 B
    ushort* zeros  = (ushort*)(ws + 4622336);   // 8192 B
    ushort* yb     = (ushort*)(ws + 4630528);   // 75497472 B (total ~80.1 MB)
    // xt scratch lives in d_out (75.5 MB of its 151 MB); dw_k overwrites
    // d_out last, after conv_k (same-stream ordering) -> no hazard.
    ushort* xt     = (ushort*)d_out;

    pool_k <<<4096, 256, 0, stream>>>(x, pooled);
    gen_k  <<<144,  256, 0, stream>>>(pooled, w_gen, b_gen, gen);
    wtr_k  <<<288,  256, 0, stream>>>(w_c1, wtr);
    xt_k   <<<1536, 512, 0, stream>>>(conv_in, xt, zeros);
    conv_k <<<1536, 256, 0, stream>>>(xt, wtr, b_c1, zeros, yb, part);
    bnred_k<<<256,  256, 0, stream>>>(part, gamma, beta, bnp);
    dw_k   <<<4096, 256, 0, stream>>>(yb, gen, bnp, out);
}

// Round 20
// 376.198 us; speedup vs baseline: 1.0138x; 1.0138x over previous
//
#include <hip/hip_runtime.h>

typedef __bf16 bf16x8 __attribute__((ext_vector_type(8)));
typedef float f32x4 __attribute__((ext_vector_type(4)));
typedef float f32x16 __attribute__((ext_vector_type(16)));

static __device__ __forceinline__ ushort f2b(float f) {
    uint32_t x = __float_as_uint(f);
    x += 0x7fffu + ((x >> 16) & 1u);   // RNE (finite values)
    return (ushort)(x >> 16);
}
static __device__ __forceinline__ float b2f(ushort u) {
    return __uint_as_float(((uint32_t)u) << 16);
}

typedef const __attribute__((address_space(1))) uint32_t gu32;
typedef __attribute__((address_space(3))) uint32_t lu32;
static __device__ __forceinline__ void gl_lds16(const void* g, void* l) {
    // async global->LDS: per-lane global src, wave-uniform LDS base + lane*16
    __builtin_amdgcn_global_load_lds((gu32*)g, (lu32*)l, 16, 0, 0);
}

// ---------------------------------------------------------------------------
// 1) adaptive_avg_pool2d(x, 3): one block per (b,c) plane. 96x96 -> 3x3.
__global__ __launch_bounds__(256) void pool_k(const float* __restrict__ x,
                                              float* __restrict__ pooled) {
    const int bc  = blockIdx.x;
    const int tid = threadIdx.x;
    const int lane = tid & 63, wv = tid >> 6;
    const float4* p4 = (const float4*)(x + (size_t)bc * 9216);
    __shared__ float red[4][9];
#pragma unroll
    for (int bi = 0; bi < 3; ++bi) {
#pragma unroll
        for (int bj = 0; bj < 3; ++bj) {
            int row = bi * 32 + (tid >> 3);
            int c4  = bj * 8 + (tid & 7);
            float4 f = p4[row * 24 + c4];
            float s = f.x + f.y + f.z + f.w;
#pragma unroll
            for (int off = 32; off; off >>= 1) s += __shfl_down(s, off);
            if (lane == 0) red[wv][bi * 3 + bj] = s;
        }
    }
    __syncthreads();
    if (tid < 9) {
        float s = red[0][tid] + red[1][tid] + red[2][tid] + red[3][tid];
        pooled[(size_t)bc * 9 + tid] = s * (1.0f / 1024.0f);
    }
}

// ---------------------------------------------------------------------------
// 2) gen = einsum('bcij,oc->boij', pooled, w_gen) + b_gen
__global__ __launch_bounds__(256) void gen_k(const float* __restrict__ pooled,
                                             const float* __restrict__ wgen,
                                             const float* __restrict__ bgen,
                                             float* __restrict__ gen) {
    __shared__ float pl[256];
    const int b = blockIdx.x / 9, ij = blockIdx.x % 9;
    const int o = threadIdx.x;
    pl[o] = pooled[((size_t)b * 256 + o) * 9 + ij];
    __syncthreads();
    float a = bgen[o];
    const float4* wg4 = (const float4*)(wgen + (size_t)o * 256);
    const float4* pl4 = (const float4*)pl;
#pragma unroll 4
    for (int q = 0; q < 64; ++q) {
        float4 w = wg4[q], p = pl4[q];
        a += w.x * p.x + w.y * p.y + w.z * p.z + w.w * p.w;
    }
    gen[((size_t)b * 256 + o) * 9 + ij] = a;
}

// ---------------------------------------------------------------------------
// 3) weight repack for 32x32x16 MFMA. wtr granule g (16B = 8 ushorts):
//    g = step*1024 + grp*64 + l, step = ch*9+tap, grp = t32*2+ks (16 groups),
//    l = lane. Content j: bf16(w_c1[o = t32*32 + (l&31)]
//                               [c = ch*32 + ks*16 + (l>>5)*8 + j][tap]).
//    A and B share the k-map (lane>>5)*8+j -> permutation-consistent.
__global__ __launch_bounds__(256) void wtr_k(const float* __restrict__ wc1,
                                             ushort* __restrict__ wtr) {
    int g = blockIdx.x * 256 + threadIdx.x;   // < 73728 granules
    int step = g >> 10;                       // 0..71
    int rem  = g & 1023;
    int grp  = rem >> 6;                      // 0..15
    int l    = rem & 63;
    int t32 = grp >> 1, ks = grp & 1;
    int ch = step / 9, tap = step - ch * 9;
    int o  = t32 * 32 + (l & 31);
    int cb = ch * 32 + ks * 16 + (l >> 5) * 8;
    ushort tmp[8];
#pragma unroll
    for (int j = 0; j < 8; ++j)
        tmp[j] = f2b(wc1[(size_t)o * 2304 + (size_t)(cb + j) * 9 + tap]);
    *(uint4*)(wtr + (size_t)g * 8) = *(const uint4*)tmp;
}

// ---------------------------------------------------------------------------
// 3b) xt_k: convoluted f32 [b][c][h][w] -> xt bf16 [b][h][px][c] (transposed),
//     via LDS. xt lives in d_out-as-scratch (dw_k overwrites d_out last).
//     Also zeroes the 8 KB "zeros" staging region (block 0).
__global__ __launch_bounds__(512) void xt_k(const float* __restrict__ xin,
                                            ushort* __restrict__ xt,
                                            ushort* __restrict__ zeros) {
    __shared__ ushort T[96][258];             // 49536 B, padded rows
    const int bh = blockIdx.x;                // b*96 + h
    const int b = bh / 96, h = bh % 96;
    const int tid = threadIdx.x;
    const float* src = xin + (size_t)b * 2359296 + (size_t)h * 96;
#pragma unroll
    for (int it = 0; it < 12; ++it) {
        int id = tid + it * 512;              // < 6144
        int c = id / 24, q = id - c * 24;     // q < 24
        float4 v = *(const float4*)(src + (size_t)c * 9216 + q * 4);
        int px = q * 4;
        T[px + 0][c] = f2b(v.x); T[px + 1][c] = f2b(v.y);
        T[px + 2][c] = f2b(v.z); T[px + 3][c] = f2b(v.w);
    }
    __syncthreads();
    ushort* dst = xt + (size_t)bh * 24576;
#pragma unroll
    for (int it = 0; it < 12; ++it) {
        int id = tid + it * 512;              // < 6144
        int px = id >> 6, cq = id & 63;
        ushort4 u;
        u.x = T[px][cq * 4 + 0]; u.y = T[px][cq * 4 + 1];
        u.z = T[px][cq * 4 + 2]; u.w = T[px][cq * 4 + 3];
        *(ushort4*)(dst + px * 256 + cq * 4) = u;
    }
    if (bh == 0) {                            // 8 KB zero region (512 x 16 B)
        uint4 zz; zz.x = zz.y = zz.z = zz.w = 0u;
        *(uint4*)(zeros + (size_t)tid * 8) = zz;
    }
}

// ---------------------------------------------------------------------------
// 4) conv3x3 (C=256->256), implicit GEMM, MFMA 32x32x16 bf16.
//    Block = (b, 1 row), 256 thr = 4 waves, wave = 64ch x 96px:
//    2 m x 3 n x f32x16 acc (96 AGPR). K-half-major B layout
//    Bl[row][ks][px 98][16c] -> conflict-free b128 reads (R18, verified).
//    REGISTER DIET for 3 streams/SIMD (512/3 = 170 regs; 96 AGPR -> VGPR
//    <= 74): A-ring depth 2 (32x32 step >= 384 cy MFMA issue >> 200 cy L2
//    latency), B-frags loaded per-ks (bfr[3] not [3][2]).
//    launch_bounds(256,3) -> 3 independent blocks/CU.
//    Epilogue: y[b][h][o][px] + BN partials (32-lane shfl + LDS gather).
__global__ __launch_bounds__(256, 3) void conv_k(const ushort* __restrict__ xt,
                                                 const ushort* __restrict__ wtr,
                                                 const float* __restrict__ bc1,
                                                 const ushort* __restrict__ zeros,
                                                 ushort* __restrict__ yb,
                                                 float* __restrict__ part) {
    __shared__ ushort Bl[2][9408];   // [buf][3 row][2 ks][98 px][16 c]

    const int blk0 = blockIdx.x;
    const int blk = (blk0 & 7) * 192 + (blk0 >> 3);  // XCD swizzle (1536=8*192)
    const int b = blk / 96, h = blk % 96;
    const int tid = threadIdx.x;
    const int lane = tid & 63, wv = tid >> 6;
    const int l31 = lane & 31, lh = lane >> 5;

    // zero pad px columns (idx 0,97): 2 bufs x 3 rows x 2 ks x 2 cols x 16 c
    {
        int z = tid;                           // 256 threads; need 384 writes
#pragma unroll
        for (int z0 = 0; z0 < 2; ++z0, z += 256) {
            if (z < 384) {
                int bsel = z >= 192, rem = z - bsel * 192;
                int row = rem >> 6, r6 = rem & 63;
                int ks = (r6 >> 5) & 1, pxp = ((r6 >> 4) & 1) ? 97 : 0,
                    c = r6 & 15;
                Bl[bsel][((row * 2 + ks) * 98 + pxp) * 16 + c] = 0;
            }
        }
    }

    // stage one chunk: 18 segs = 3 rows x 2 ks x 3 px-groups(32). Wave wv
    // does segs {wv, wv+4, ...}. Seg = 1KB lane-linear: px=lane>>1 within
    // group, c-half=lane&1 (8 ushorts).
    auto stage = [&](int chunk, int buf) {
#pragma unroll
        for (int j = 0; j < 5; ++j) {
            const int s = wv + j * 4;
            if (s < 18) {
                const int row = s / 6, r6 = s - (s / 6) * 6;
                const int ks = r6 / 3, pg = r6 - ks * 3;
                const int r = h + row - 1;
                const ushort* src = ((unsigned)r < 96u)
                    ? (xt + ((size_t)(b * 96 + r) * 96 + pg * 32
                             + (lane >> 1)) * 256
                          + chunk * 32 + ks * 16 + (lane & 1) * 8)
                    : (zeros + lane * 8);
                gl_lds16(src,
                         &Bl[buf][((row * 2 + ks) * 98 + 1 + pg * 32) * 16]);
            }
        }
    };

    // ---- A fragments: frag (mi,ks) = granule step*1024 + (wv*4+mi*2+ks)*64
    //      + lane. Per step: 4 frags = 4 KB/wave.
    const uint4* Abase = (const uint4*)wtr + wv * 256 + lane;

    f32x16 acc[2][3] = {};
    uint4 abuf[2][4];        // depth-2 ping-pong: slot = t & 1; frag = mi*2+ks

    // ---- prologue: stage chunk 0 -> buf0; A(step 0) -> slot 0
    stage(0, 0);
#pragma unroll
    for (int f = 0; f < 4; ++f) abuf[0][f] = Abase[f * 64];
    __syncthreads();   // drains DMA

    for (int k = 0; k < 4; ++k) {              // chunks 2k (buf0), 2k+1 (buf1)
#pragma unroll
        for (int t = 0; t < 18; ++t) {         // stp = k*18 + t; idx static
            const int cur = t & 1;
            if (t == 0) stage(2 * k + 1, 1);
            else if (t == 9 && k < 3) stage(2 * k + 2, 0);
            if (t < 17 || k < 3) {             // A prefetch stp+1 -> slot cur^1
                const uint4* Ap = Abase + (size_t)(k * 18 + t + 1) * 1024;
#pragma unroll
                for (int f = 0; f < 4; ++f)
                    abuf[cur ^ 1][f] = Ap[f * 64];
            }
            const int tap = (t < 9) ? t : t - 9;
            const int dy = tap / 3, dx = tap % 3;
            const ushort* Bb = &Bl[t >= 9][0];
#pragma unroll
            for (int ks = 0; ks < 2; ++ks) {
                bf16x8 bfr[3];
#pragma unroll
                for (int ni = 0; ni < 3; ++ni)
                    bfr[ni] = *(const bf16x8*)(Bb +
                        ((dy * 2 + ks) * 98 + ni * 32 + l31 + dx) * 16 + lh * 8);
#pragma unroll
                for (int mi = 0; mi < 2; ++mi) {
                    const bf16x8 af = *(const bf16x8*)&abuf[cur][mi * 2 + ks];
#pragma unroll
                    for (int ni = 0; ni < 3; ++ni)
                        acc[mi][ni] = __builtin_amdgcn_mfma_f32_32x32x16_bf16(
                            af, bfr[ni], acc[mi][ni], 0, 0, 0);
                }
            }
            if (t == 8) __syncthreads();               // buf1 ready, buf0 free
            else if (t == 17 && k < 3) __syncthreads();// buf0 ready, buf1 free
        }
    }

    // ---- epilogue: +bias, y store ([b][h][o][px]) + BN partials.
    //      D (verified): col = lane&31 (px), row = (r&3)+8*(r>>2)+4*(lane>>5)
    const size_t ybase = (size_t)blk * 24576;
    float* red = (float*)&Bl[0][0];           // 256 o x {s, s2}
    __syncthreads();                          // all MFMA reads of Bl done
#pragma unroll
    for (int mi = 0; mi < 2; ++mi) {
        const int ob = wv * 64 + mi * 32;
        float s[16], s2[16];
#pragma unroll
        for (int r = 0; r < 16; ++r) {
            const int o = ob + (r & 3) + 8 * (r >> 2) + 4 * lh;
            const float bias = bc1[o];
            float sv = 0.f, sv2 = 0.f;
#pragma unroll
            for (int ni = 0; ni < 3; ++ni) {
                float v = acc[mi][ni][r] + bias;
                yb[ybase + o * 96 + ni * 32 + l31] = f2b(v);
                sv += v; sv2 += v * v;
            }
            s[r] = sv; s2[r] = sv2;
        }
#pragma unroll
        for (int off = 1; off < 32; off <<= 1) {
#pragma unroll
            for (int r = 0; r < 16; ++r) {
                s[r]  += __shfl_xor(s[r], off);
                s2[r] += __shfl_xor(s2[r], off);
            }
        }
        if (l31 == 0) {
#pragma unroll
            for (int r = 0; r < 16; ++r) {
                const int ol = ob + (r & 3) + 8 * (r >> 2) + 4 * lh;
                red[ol * 2]     = s[r];
                red[ol * 2 + 1] = s2[r];
            }
        }
    }
    __syncthreads();
    {
        const int o = tid;                    // 256 threads = 256 channels
        part[(size_t)o * 1536 + blk]          = red[o * 2];
        part[393216 + (size_t)o * 1536 + blk] = red[o * 2 + 1];
    }
}

// ---------------------------------------------------------------------------
// 5) BN reduce + finalize: block = channel o; sum 1536 partials (coalesced)
__global__ __launch_bounds__(256) void bnred_k(const float* __restrict__ part,
                                               const float* __restrict__ gamma,
                                               const float* __restrict__ beta,
                                               float* __restrict__ bnp) {
    const int o = blockIdx.x, t = threadIdx.x;
    const float* p0 = part + (size_t)o * 1536;
    const float* p1 = p0 + 393216;
    float s = 0.f, s2 = 0.f;
#pragma unroll
    for (int k = 0; k < 6; ++k) { s += p0[t + k * 256]; s2 += p1[t + k * 256]; }
    const int lane = t & 63, wv = t >> 6;
#pragma unroll
    for (int off = 32; off; off >>= 1) {
        s  += __shfl_down(s, off);
        s2 += __shfl_down(s2, off);
    }
    __shared__ float r1[4], r2[4];
    if (lane == 0) { r1[wv] = s; r2[wv] = s2; }
    __syncthreads();
    if (t == 0) {
        float S  = r1[0] + r1[1] + r1[2] + r1[3];
        float S2 = r2[0] + r2[1] + r2[2] + r2[3];
        const float invN = 1.0f / 147456.0f;
        float mu  = S * invN;
        float var = S2 * invN - mu * mu;
        float sc  = gamma[o] * rsqrtf(var + 1e-5f);
        bnp[o]       = sc;
        bnp[256 + o] = beta[o] - mu * sc;
    }
}

// ---------------------------------------------------------------------------
// 6) depthwise 3x3, vectorized: padded LDS [98][104] f32 (zero halo, no
//    branches), each thread computes 4 outputs/iter from 9 ds_read_b128 +
//    36 FMA; float4 stores. yb layout [b][h][o][px] (row stride 24576).
__global__ __launch_bounds__(256) void dw_k(const ushort* __restrict__ yb,
                                            const float* __restrict__ gen,
                                            const float* __restrict__ bnp,
                                            float* __restrict__ out) {
    __shared__ float pl[98][104];                 // 40768 B
    const int bc = blockIdx.x, tid = threadIdx.x;
    const int b = bc >> 8, c = bc & 255;
    const float sc = bnp[c], sh = bnp[256 + c];

    // zero halo: rows 0 & 97 (104 each) + cols {0..3,100..103} rows 1..96
#pragma unroll
    for (int z0 = 0; z0 < 4; ++z0) {
        int z = tid + z0 * 256;
        if (z < 104) pl[0][z] = 0.f;
        else if (z < 208) pl[97][z - 104] = 0.f;
        else if (z < 976) {
            int w = z - 208;                      // < 768
            int r = (w >> 3) + 1, j = w & 7;
            pl[r][(j < 4) ? j : 96 + j] = 0.f;
        }
    }

    // stage plane with BN+ReLU: 2304 ushort4 items, 9 per thread
    const ushort4* yb4 = (const ushort4*)yb;
    const size_t pbase = (size_t)b * 589824 + c * 24;   // ushort4 units
#pragma unroll
    for (int it = 0; it < 9; ++it) {
        int e4 = tid + it * 256;                  // < 2304
        int row = e4 / 24, q = e4 - row * 24;
        ushort4 u = yb4[pbase + (size_t)row * 6144 + q];
        float4 f;
        f.x = fmaxf(b2f(u.x) * sc + sh, 0.f);
        f.y = fmaxf(b2f(u.y) * sc + sh, 0.f);
        f.z = fmaxf(b2f(u.z) * sc + sh, 0.f);
        f.w = fmaxf(b2f(u.w) * sc + sh, 0.f);
        *(float4*)&pl[row + 1][q * 4 + 4] = f;
    }
    float g[9];
    const float* gp = gen + (size_t)bc * 9;
#pragma unroll
    for (int k = 0; k < 9; ++k) g[k] = gp[k];
    __syncthreads();

    float4* op4 = (float4*)(out + (size_t)bc * 9216);
#pragma unroll
    for (int it = 0; it < 9; ++it) {
        int e4 = tid + it * 256;                  // < 2304
        int row = e4 / 24, q = e4 - row * 24;     // out row, col group 4q..4q+3
        float4 o4 = {0.f, 0.f, 0.f, 0.f};
#pragma unroll
        for (int dy = 0; dy < 3; ++dy) {
            const float4* pr = (const float4*)&pl[row + dy][0];
            float4 x0 = pr[q];                    // need .w  (col 4q-1)
            float4 x1 = pr[q + 1];                // cols 4q..4q+3
            float4 x2 = pr[q + 2];                // need .x  (col 4q+4)
            const float w0 = g[dy * 3 + 0], w1 = g[dy * 3 + 1],
                        w2 = g[dy * 3 + 2];
            o4.x += w0 * x0.w + w1 * x1.x + w2 * x1.y;
            o4.y += w0 * x1.x + w1 * x1.y + w2 * x1.z;
            o4.z += w0 * x1.y + w1 * x1.z + w2 * x1.w;
            o4.w += w0 * x1.z + w1 * x1.w + w2 * x2.x;
        }
        op4[e4] = o4;
    }
}

// ---------------------------------------------------------------------------
extern "C" void kernel_launch(void* const* d_in, const int* in_sizes, int n_in,
                              void* d_out, int out_size, void* d_ws, size_t ws_size,
                              hipStream_t stream) {
    const float* x       = (const float*)d_in[0];
    const float* conv_in = (const float*)d_in[1];
    const float* w_gen   = (const float*)d_in[2];
    const float* b_gen   = (const float*)d_in[3];
    const float* w_c1    = (const float*)d_in[4];
    const float* b_c1    = (const float*)d_in[5];
    const float* gamma   = (const float*)d_in[6];
    const float* beta    = (const float*)d_in[7];
    float* out = (float*)d_out;

    char* ws = (char*)d_ws;
    float*  pooled = (float*)(ws + 0);          // 147456 B
    float*  gen    = (float*)(ws + 147456);     // 147456 B
    ushort* wtr    = (ushort*)(ws + 294912);    // 1179648 B
    float*  part   = (float*)(ws + 1474560);    // 3145728 B
    float*  bnp    = (float*)(ws + 4620288);    // 2048 B
    ushort* zeros  = (ushort*)(ws + 4622336);   // 8192 B
    ushort* yb     = (ushort*)(ws + 4630528);   // 75497472 B (total ~80.1 MB)
    // xt scratch lives in d_out (75.5 MB of its 151 MB); dw_k overwrites
    // d_out last, after conv_k (same-stream ordering) -> no hazard.
    ushort* xt     = (ushort*)d_out;

    pool_k <<<4096, 256, 0, stream>>>(x, pooled);
    gen_k  <<<144,  256, 0, stream>>>(pooled, w_gen, b_gen, gen);
    wtr_k  <<<288,  256, 0, stream>>>(w_c1, wtr);
    xt_k   <<<1536, 512, 0, stream>>>(conv_in, xt, zeros);
    conv_k <<<1536, 256, 0, stream>>>(xt, wtr, b_c1, zeros, yb, part);
    bnred_k<<<256,  256, 0, stream>>>(part, gamma, beta, bnp);
    dw_k   <<<4096, 256, 0, stream>>>(yb, gen, bnp, out);
}

// Round 21
// 312.312 us; speedup vs baseline: 1.2212x; 1.2046x over previous
//
#include <hip/hip_runtime.h>

typedef __bf16 bf16x8 __attribute__((ext_vector_type(8)));
typedef float f32x4 __attribute__((ext_vector_type(4)));

static __device__ __forceinline__ ushort f2b(float f) {
    uint32_t x = __float_as_uint(f);
    x += 0x7fffu + ((x >> 16) & 1u);   // RNE (finite values)
    return (ushort)(x >> 16);
}
static __device__ __forceinline__ float b2f(ushort u) {
    return __uint_as_float(((uint32_t)u) << 16);
}

typedef const __attribute__((address_space(1))) uint32_t gu32;
typedef __attribute__((address_space(3))) uint32_t lu32;
static __device__ __forceinline__ void gl_lds16(const void* g, void* l) {
    // async global->LDS: per-lane global src, wave-uniform LDS base + lane*16
    __builtin_amdgcn_global_load_lds((gu32*)g, (lu32*)l, 16, 0, 0);
}

// ---------------------------------------------------------------------------
// 1) adaptive_avg_pool2d(x, 3): one block per (b,c) plane. 96x96 -> 3x3.
__global__ __launch_bounds__(256) void pool_k(const float* __restrict__ x,
                                              float* __restrict__ pooled) {
    const int bc  = blockIdx.x;
    const int tid = threadIdx.x;
    const int lane = tid & 63, wv = tid >> 6;
    const float4* p4 = (const float4*)(x + (size_t)bc * 9216);
    __shared__ float red[4][9];
#pragma unroll
    for (int bi = 0; bi < 3; ++bi) {
#pragma unroll
        for (int bj = 0; bj < 3; ++bj) {
            int row = bi * 32 + (tid >> 3);
            int c4  = bj * 8 + (tid & 7);
            float4 f = p4[row * 24 + c4];
            float s = f.x + f.y + f.z + f.w;
#pragma unroll
            for (int off = 32; off; off >>= 1) s += __shfl_down(s, off);
            if (lane == 0) red[wv][bi * 3 + bj] = s;
        }
    }
    __syncthreads();
    if (tid < 9) {
        float s = red[0][tid] + red[1][tid] + red[2][tid] + red[3][tid];
        pooled[(size_t)bc * 9 + tid] = s * (1.0f / 1024.0f);
    }
}

// ---------------------------------------------------------------------------
// 2) gen = einsum('bcij,oc->boij', pooled, w_gen) + b_gen
__global__ __launch_bounds__(256) void gen_k(const float* __restrict__ pooled,
                                             const float* __restrict__ wgen,
                                             const float* __restrict__ bgen,
                                             float* __restrict__ gen) {
    __shared__ float pl[256];
    const int b = blockIdx.x / 9, ij = blockIdx.x % 9;
    const int o = threadIdx.x;
    pl[o] = pooled[((size_t)b * 256 + o) * 9 + ij];
    __syncthreads();
    float a = bgen[o];
    const float4* wg4 = (const float4*)(wgen + (size_t)o * 256);
    const float4* pl4 = (const float4*)pl;
#pragma unroll 4
    for (int q = 0; q < 64; ++q) {
        float4 w = wg4[q], p = pl4[q];
        a += w.x * p.x + w.y * p.y + w.z * p.z + w.w * p.w;
    }
    gen[((size_t)b * 256 + o) * 9 + ij] = a;
}

// ---------------------------------------------------------------------------
// 3) weight repack: wtr[step][row][c], step = ch*9 + tap, 32 c per step.
//    Granule g (16B = 8 c): g = step*1024 + row*4 + c8,
//    content j = bf16(w_c1[row][ch*32 + c8*8 + j][tap]).  (16x16 layout)
__global__ __launch_bounds__(256) void wtr_k(const float* __restrict__ wc1,
                                             ushort* __restrict__ wtr) {
    int g = blockIdx.x * 256 + threadIdx.x;   // < 73728 granules
    int step = g >> 10;                       // 0..71
    int row  = (g >> 2) & 255;
    int c8   = g & 3;
    int ch = step / 9, tap = step - ch * 9;
    int cb = ch * 32 + c8 * 8;
    ushort tmp[8];
#pragma unroll
    for (int j = 0; j < 8; ++j)
        tmp[j] = f2b(wc1[(size_t)row * 2304 + (size_t)(cb + j) * 9 + tap]);
    *(uint4*)(wtr + (size_t)g * 8) = *(const uint4*)tmp;
}

// ---------------------------------------------------------------------------
// 3b) xt_k: convoluted f32 [b][c][h][w] -> xt bf16 [b][h][px][c] (transposed),
//     via LDS. xt lives in d_out-as-scratch (dw_k overwrites d_out last).
//     Also zeroes the 8 KB "zeros" staging region (block 0).
__global__ __launch_bounds__(512) void xt_k(const float* __restrict__ xin,
                                            ushort* __restrict__ xt,
                                            ushort* __restrict__ zeros) {
    __shared__ ushort T[96][258];             // 49536 B, padded rows
    const int bh = blockIdx.x;                // b*96 + h
    const int b = bh / 96, h = bh % 96;
    const int tid = threadIdx.x;
    const float* src = xin + (size_t)b * 2359296 + (size_t)h * 96;
#pragma unroll
    for (int it = 0; it < 12; ++it) {
        int id = tid + it * 512;              // < 6144
        int c = id / 24, q = id - c * 24;     // q < 24
        float4 v = *(const float4*)(src + (size_t)c * 9216 + q * 4);
        int px = q * 4;
        T[px + 0][c] = f2b(v.x); T[px + 1][c] = f2b(v.y);
        T[px + 2][c] = f2b(v.z); T[px + 3][c] = f2b(v.w);
    }
    __syncthreads();
    ushort* dst = xt + (size_t)bh * 24576;
#pragma unroll
    for (int it = 0; it < 12; ++it) {
        int id = tid + it * 512;              // < 6144
        int px = id >> 6, cq = id & 63;
        ushort4 u;
        u.x = T[px][cq * 4 + 0]; u.y = T[px][cq * 4 + 1];
        u.z = T[px][cq * 4 + 2]; u.w = T[px][cq * 4 + 3];
        *(ushort4*)(dst + px * 256 + cq * 4) = u;
    }
    if (bh == 0) {                            // 8 KB zero region (512 x 16 B)
        uint4 zz; zz.x = zz.y = zz.z = zz.w = 0u;
        *(uint4*)(zeros + (size_t)tid * 8) = zz;
    }
}

// ---------------------------------------------------------------------------
// 4) conv3x3 (C=256->256), implicit GEMM, MFMA 16x16x32 bf16 — R15 structure
//    (best measured: 172 us) + s_setprio around the MFMA cluster (T5: 3
//    desynced block-streams/SIMD = the regime where setprio measured +4-7%).
//    Block = (b, 1 row, o-half), 256 thr = 4 waves, wave = 32ch x 96px,
//    acc[2][6] (48 AGPR), launch_bounds(256,3) -> 3 independent blocks/CU.
//    Grid 3072 = 1536 rows x 2 o-halves. B-halo [2 buf][3 rows][98 px][32 c]
//    via global_load_lds; ONE barrier per 9-tap chunk. A: global->VGPR
//    depth-3 ring (prefetch t+2; 1024 uint4/step).
__global__ __launch_bounds__(256, 3) void conv_k(const ushort* __restrict__ xt,
                                                 const ushort* __restrict__ wtr,
                                                 const float* __restrict__ bc1,
                                                 const ushort* __restrict__ zeros,
                                                 ushort* __restrict__ yb,
                                                 float* __restrict__ part) {
    __shared__ ushort Bl[2][9408];   // [buf][3*98*32] = 18816 B each

    const int blk0 = blockIdx.x;
    const int blk = (blk0 & 7) * 384 + (blk0 >> 3);  // XCD swizzle (3072=8*384)
    const int ohalf = blk & 1, rowblk = blk >> 1;    // ohalf-pairs share a row
    const int b = rowblk / 96, h = rowblk % 96;
    const int tid = threadIdx.x;
    const int lane = tid & 63, wv = tid >> 6;        // wv = m-slice 0..3
    const int lo = lane & 15, hi = lane >> 4;

    // zero pad px columns (idx 0,97): 2 bufs x 3 rows x 2 cols x 32 c = 384
#pragma unroll
    for (int z0 = 0; z0 < 2; ++z0) {
        int z = tid + z0 * 256;
        if (z < 384) {
            int bsel = z >= 192, rem = z - bsel * 192;
            int row = rem >> 6, pxp = ((rem >> 5) & 1) ? 97 : 0, c = rem & 31;
            Bl[bsel][(row * 98 + pxp) * 32 + c] = 0;
        }
    }

    // per-lane source offset within a seg: px=lane>>2, c8=lane&3 (ushorts)
    const int laneoff = (lane >> 2) * 256 + (lane & 3) * 8;

    // stage one chunk (18 segs = 3 rows x 6 psegs of 16 px); wave wv does
    // segs {wv, wv+4, ...}. Seg bases wave-uniform (SALU).
    auto stage = [&](int chunk, int buf) {
#pragma unroll
        for (int j = 0; j < 5; ++j) {
            const int s = wv + j * 4;
            if (s < 18) {
                const int row = s / 6, pseg = s - (s / 6) * 6;
                const int r = h + row - 1;
                const ushort* base = ((unsigned)r < 96u)
                    ? (xt + ((size_t)(b * 96 + r) * 96 + pseg * 16) * 256
                          + chunk * 32)
                    : zeros;
                gl_lds16(base + laneoff,
                         &Bl[buf][(row * 98 + 1 + pseg * 16) * 32]);
            }
        }
    };

    // ---- A fragments: granule = o*4 + hi within a step (1024 uint4/step)
    const uint4* Abase =
        (const uint4*)wtr + ((ohalf * 128 + wv * 32 + lo) * 4 + hi);

    f32x4 acc[2][6] = {};
    uint4 abuf[3][2];        // depth-3 ring: slot = step % 3

    // ---- prologue: stage chunk 0 -> buf0; A(step 0,1) -> slots 0,1
    stage(0, 0);
#pragma unroll
    for (int mi = 0; mi < 2; ++mi) abuf[0][mi] = Abase[mi * 64];
#pragma unroll
    for (int mi = 0; mi < 2; ++mi) abuf[1][mi] = (Abase + 1024)[mi * 64];
    __syncthreads();   // drains DMA

    for (int k = 0; k < 4; ++k) {              // chunks 2k (buf0), 2k+1 (buf1)
#pragma unroll
        for (int t = 0; t < 18; ++t) {         // stp = k*18 + t; idx static
            if (t == 0) stage(2 * k + 1, 1);
            else if (t == 9 && k < 3) stage(2 * k + 2, 0);
            if (t < 16 || k < 3) {             // A prefetch stp+2 -> (t+2)%3
                const uint4* Ap = Abase + (size_t)(k * 18 + t + 2) * 1024;
#pragma unroll
                for (int mi = 0; mi < 2; ++mi)
                    abuf[(t + 2) % 3][mi] = Ap[mi * 64];
            }
            const int tap = (t < 9) ? t : t - 9;
            const int dy = tap / 3, dx = tap % 3;
            const ushort* Bp = &Bl[t >= 9][(dy * 98 + lo + dx) * 32 + hi * 8];
            bf16x8 bfr[6];
#pragma unroll
            for (int ni = 0; ni < 6; ++ni)
                bfr[ni] = *(const bf16x8*)(Bp + ni * 512);
            __builtin_amdgcn_s_setprio(1);     // T5: favor MFMA-entering wave
#pragma unroll
            for (int mi = 0; mi < 2; ++mi) {
                const bf16x8 af = *(const bf16x8*)&abuf[t % 3][mi];
#pragma unroll
                for (int ni = 0; ni < 6; ++ni)
                    acc[mi][ni] = __builtin_amdgcn_mfma_f32_16x16x32_bf16(
                        af, bfr[ni], acc[mi][ni], 0, 0, 0);
            }
            __builtin_amdgcn_s_setprio(0);
            if (t == 8) __syncthreads();               // buf1 ready, buf0 free
            else if (t == 17 && k < 3) __syncthreads();// buf0 ready, buf1 free
        }
    }

    // ---- epilogue: +bias, y store ([b][h][o][px]) + fused BN partials.
    //      D: col(px)=lane&15, row=hi*4+rr
    const size_t ybase = (size_t)rowblk * 24576;
#pragma unroll
    for (int mi = 0; mi < 2; ++mi) {
        float s[4], s2[4];
#pragma unroll
        for (int rr = 0; rr < 4; ++rr) {
            const int o = ohalf * 128 + wv * 32 + mi * 16 + hi * 4 + rr;
            const float bias = bc1[o];
            float sv = 0.f, sv2 = 0.f;
#pragma unroll
            for (int ni = 0; ni < 6; ++ni) {
                const int px = ni * 16 + lo;
                float v = acc[mi][ni][rr] + bias;
                yb[ybase + o * 96 + px] = f2b(v);
                sv += v; sv2 += v * v;
            }
            s[rr] = sv; s2[rr] = sv2;
        }
#pragma unroll
        for (int off = 1; off < 16; off <<= 1) {
#pragma unroll
            for (int rr = 0; rr < 4; ++rr) {
                s[rr]  += __shfl_xor(s[rr], off);
                s2[rr] += __shfl_xor(s2[rr], off);
            }
        }
        if (lo == 0) {
#pragma unroll
            for (int rr = 0; rr < 4; ++rr) {
                const int o = ohalf * 128 + wv * 32 + mi * 16 + hi * 4 + rr;
                part[(size_t)o * 1536 + rowblk]          = s[rr];
                part[393216 + (size_t)o * 1536 + rowblk] = s2[rr];
            }
        }
    }
}

// ---------------------------------------------------------------------------
// 5) BN reduce + finalize: block = channel o; sum 1536 partials (coalesced)
__global__ __launch_bounds__(256) void bnred_k(const float* __restrict__ part,
                                               const float* __restrict__ gamma,
                                               const float* __restrict__ beta,
                                               float* __restrict__ bnp) {
    const int o = blockIdx.x, t = threadIdx.x;
    const float* p0 = part + (size_t)o * 1536;
    const float* p1 = p0 + 393216;
    float s = 0.f, s2 = 0.f;
#pragma unroll
    for (int k = 0; k < 6; ++k) { s += p0[t + k * 256]; s2 += p1[t + k * 256]; }
    const int lane = t & 63, wv = t >> 6;
#pragma unroll
    for (int off = 32; off; off >>= 1) {
        s  += __shfl_down(s, off);
        s2 += __shfl_down(s2, off);
    }
    __shared__ float r1[4], r2[4];
    if (lane == 0) { r1[wv] = s; r2[wv] = s2; }
    __syncthreads();
    if (t == 0) {
        float S  = r1[0] + r1[1] + r1[2] + r1[3];
        float S2 = r2[0] + r2[1] + r2[2] + r2[3];
        const float invN = 1.0f / 147456.0f;
        float mu  = S * invN;
        float var = S2 * invN - mu * mu;
        float sc  = gamma[o] * rsqrtf(var + 1e-5f);
        bnp[o]       = sc;
        bnp[256 + o] = beta[o] - mu * sc;
    }
}

// ---------------------------------------------------------------------------
// 6) depthwise 3x3, vectorized: padded LDS [98][104] f32 (zero halo, no
//    branches), each thread computes 4 outputs/iter from 9 ds_read_b128 +
//    36 FMA; float4 stores. yb layout [b][h][o][px] (row stride 24576).
__global__ __launch_bounds__(256) void dw_k(const ushort* __restrict__ yb,
                                            const float* __restrict__ gen,
                                            const float* __restrict__ bnp,
                                            float* __restrict__ out) {
    __shared__ float pl[98][104];                 // 40768 B
    const int bc = blockIdx.x, tid = threadIdx.x;
    const int b = bc >> 8, c = bc & 255;
    const float sc = bnp[c], sh = bnp[256 + c];

    // zero halo: rows 0 & 97 (104 each) + cols {0..3,100..103} rows 1..96
#pragma unroll
    for (int z0 = 0; z0 < 4; ++z0) {
        int z = tid + z0 * 256;
        if (z < 104) pl[0][z] = 0.f;
        else if (z < 208) pl[97][z - 104] = 0.f;
        else if (z < 976) {
            int w = z - 208;                      // < 768
            int r = (w >> 3) + 1, j = w & 7;
            pl[r][(j < 4) ? j : 96 + j] = 0.f;
        }
    }

    // stage plane with BN+ReLU: 2304 ushort4 items, 9 per thread
    const ushort4* yb4 = (const ushort4*)yb;
    const size_t pbase = (size_t)b * 589824 + c * 24;   // ushort4 units
#pragma unroll
    for (int it = 0; it < 9; ++it) {
        int e4 = tid + it * 256;                  // < 2304
        int row = e4 / 24, q = e4 - row * 24;
        ushort4 u = yb4[pbase + (size_t)row * 6144 + q];
        float4 f;
        f.x = fmaxf(b2f(u.x) * sc + sh, 0.f);
        f.y = fmaxf(b2f(u.y) * sc + sh, 0.f);
        f.z = fmaxf(b2f(u.z) * sc + sh, 0.f);
        f.w = fmaxf(b2f(u.w) * sc + sh, 0.f);
        *(float4*)&pl[row + 1][q * 4 + 4] = f;
    }
    float g[9];
    const float* gp = gen + (size_t)bc * 9;
#pragma unroll
    for (int k = 0; k < 9; ++k) g[k] = gp[k];
    __syncthreads();

    float4* op4 = (float4*)(out + (size_t)bc * 9216);
#pragma unroll
    for (int it = 0; it < 9; ++it) {
        int e4 = tid + it * 256;                  // < 2304
        int row = e4 / 24, q = e4 - row * 24;     // out row, col group 4q..4q+3
        float4 o4 = {0.f, 0.f, 0.f, 0.f};
#pragma unroll
        for (int dy = 0; dy < 3; ++dy) {
            const float4* pr = (const float4*)&pl[row + dy][0];
            float4 x0 = pr[q];                    // need .w  (col 4q-1)
            float4 x1 = pr[q + 1];                // cols 4q..4q+3
            float4 x2 = pr[q + 2];                // need .x  (col 4q+4)
            const float w0 = g[dy * 3 + 0], w1 = g[dy * 3 + 1],
                        w2 = g[dy * 3 + 2];
            o4.x += w0 * x0.w + w1 * x1.x + w2 * x1.y;
            o4.y += w0 * x1.x + w1 * x1.y + w2 * x1.z;
            o4.z += w0 * x1.y + w1 * x1.z + w2 * x1.w;
            o4.w += w0 * x1.z + w1 * x1.w + w2 * x2.x;
        }
        op4[e4] = o4;
    }
}

// ---------------------------------------------------------------------------
extern "C" void kernel_launch(void* const* d_in, const int* in_sizes, int n_in,
                              void* d_out, int out_size, void* d_ws, size_t ws_size,
                              hipStream_t stream) {
    const float* x       = (const float*)d_in[0];
    const float* conv_in = (const float*)d_in[1];
    const float* w_gen   = (const float*)d_in[2];
    const float* b_gen   = (const float*)d_in[3];
    const float* w_c1    = (const float*)d_in[4];
    const float* b_c1    = (const float*)d_in[5];
    const float* gamma   = (const float*)d_in[6];
    const float* beta    = (const float*)d_in[7];
    float* out = (float*)d_out;

    char* ws = (char*)d_ws;
    float*  pooled = (float*)(ws + 0);          // 147456 B
    float*  gen    = (float*)(ws + 147456);     // 147456 B
    ushort* wtr    = (ushort*)(ws + 294912);    // 1179648 B
    float*  part   = (float*)(ws + 1474560);    // 3145728 B
    float*  bnp    = (float*)(ws + 4620288);    // 2048 B
    ushort* zeros  = (ushort*)(ws + 4622336);   // 8192 B
    ushort* yb     = (ushort*)(ws + 4630528);   // 75497472 B (total ~80.1 MB)
    // xt scratch lives in d_out (75.5 MB of its 151 MB); dw_k overwrites
    // d_out last, after conv_k (same-stream ordering) -> no hazard.
    ushort* xt     = (ushort*)d_out;

    pool_k <<<4096, 256, 0, stream>>>(x, pooled);
    gen_k  <<<144,  256, 0, stream>>>(pooled, w_gen, b_gen, gen);
    wtr_k  <<<288,  256, 0, stream>>>(w_c1, wtr);
    xt_k   <<<1536, 512, 0, stream>>>(conv_in, xt, zeros);
    conv_k <<<3072, 256, 0, stream>>>(xt, wtr, b_c1, zeros, yb, part);
    bnred_k<<<256,  256, 0, stream>>>(part, gamma, beta, bnp);
    dw_k   <<<4096, 256, 0, stream>>>(yb, gen, bnp, out);
}